// Round 5
// baseline (24.292 us; speedup 1.0000x reference)
//
#include <hip/hip_runtime.h>

// BatchedFoveator: out[b,t,c,i,j] = mean of img[b,c, cy+s*i : +s, cx+s*j : +s]
// B=32, C=3, IMG=512, NT=160 tokens (64 @s=1, 48 @s=2, 48 @s=4), 16x16 px/token.
// Wave = one (b,t,c) 16x16 plane (s wave-uniform). Each thread: 4 outputs at
// rows i0, i0+4, i0+8, i0+12 (j lane-minor). Every load/store instruction is
// the same contiguous 64-256B wave-run pattern as the 22.0us R1 kernel, with
// 4x fewer threads and nontemporal (single-touch) memory ops.

#define NTOK    160
#define NB      32
#define NC      3

typedef float fvec4 __attribute__((ext_vector_type(4)));
typedef float fvec2 __attribute__((ext_vector_type(2)));

// Decode token index -> (corner_x, corner_y, stride). Matches the reference's
// _precompute_tokens(): level 0 = full 8x8 grid (s=1, corner 192+16*{j,i});
// levels 1,2 = 8x8 grid minus central 4x4 ring, enumerated rows 0-1 full,
// rows 2-5 cols {0,1,6,7}, rows 6-7 full.
__device__ __forceinline__ void token_params(int t, int& cx, int& cy, int& s) {
    if (t < 64) {
        int i = t >> 3, j = t & 7;
        cx = 192 + 16 * j;
        cy = 192 + 16 * i;
        s = 1;
    } else {
        int u = t - 64;
        bool lvl2 = (u >= 48);
        if (lvl2) u -= 48;
        int i, j;
        if (u < 16) {              // rows 0,1 full
            i = u >> 3; j = u & 7;
        } else if (u < 32) {       // rows 2..5, cols 0,1,6,7
            int v = u - 16;
            i = 2 + (v >> 2);
            int p = v & 3;
            j = (p < 2) ? p : (p + 4);
        } else {                   // rows 6,7 full
            int v = u - 32;
            i = 6 + (v >> 3); j = v & 7;
        }
        if (!lvl2) { cx = 128 + 32 * j; cy = 128 + 32 * i; s = 2; }
        else       { cx = 64 * j;       cy = 64 * i;       s = 4; }
    }
}

__global__ __launch_bounds__(256) void fovea_kernel(const float* __restrict__ img,
                                                    float* __restrict__ out) {
    int g = blockIdx.x * 256 + threadIdx.x;
    int w     = g & 63;          // within-plane thread: i0*16 + j
    int plane = g >> 6;          // (b*NTOK + t)*NC + c
    int j  = w & 15;
    int i0 = w >> 4;             // 0..3
    int c  = plane % NC;
    int bt = plane / NC;
    int t  = bt % NTOK;
    int b  = bt / NTOK;

    int cx, cy, s;
    token_params(t, cx, cy, s);

    const float* base = img + ((size_t)(b * NC + c) << 18);  // 512*512 = 1<<18
    float res[4];

    if (s == 1) {
        int x0 = cx + j;
        #pragma unroll
        for (int k = 0; k < 4; ++k) {
            int y0 = cy + 4 * k + i0;
            res[k] = __builtin_nontemporal_load(base + ((size_t)y0 << 9) + x0);
        }
    } else if (s == 2) {
        int x0 = cx + 2 * j;
        #pragma unroll
        for (int k = 0; k < 4; ++k) {
            int y0 = cy + 2 * (4 * k + i0);
            fvec2 a = __builtin_nontemporal_load(
                reinterpret_cast<const fvec2*>(base + ((size_t)y0 << 9) + x0));
            fvec2 d = __builtin_nontemporal_load(
                reinterpret_cast<const fvec2*>(base + ((size_t)(y0 + 1) << 9) + x0));
            res[k] = (a.x + a.y + d.x + d.y) * 0.25f;
        }
    } else {
        int x0 = cx + 4 * j;
        #pragma unroll
        for (int k = 0; k < 4; ++k) {
            int y0 = cy + 4 * (4 * k + i0);
            float sum = 0.f;
            #pragma unroll
            for (int dy = 0; dy < 4; ++dy) {
                fvec4 v = __builtin_nontemporal_load(
                    reinterpret_cast<const fvec4*>(base + ((size_t)(y0 + dy) << 9) + x0));
                sum += v.x + v.y + v.z + v.w;
            }
            res[k] = sum * 0.0625f;
        }
    }

    float* op = out + ((size_t)plane << 8) + (i0 << 4) + j;
    #pragma unroll
    for (int k = 0; k < 4; ++k)
        __builtin_nontemporal_store(res[k], op + (k << 6));
}

extern "C" void kernel_launch(void* const* d_in, const int* in_sizes, int n_in,
                              void* d_out, int out_size, void* d_ws, size_t ws_size,
                              hipStream_t stream) {
    const float* img = (const float*)d_in[0];
    float* out = (float*)d_out;
    // out_size = 32*160*3*16*16 = 3,932,160 -> 4 outputs/thread
    int total_threads = NB * NTOK * NC * 64;
    int blocks = total_threads / 256;  // 3840
    fovea_kernel<<<blocks, 256, 0, stream>>>(img, out);
}